// Round 12
// baseline (1366.129 us; speedup 1.0000x reference)
//
#include <hip/hip_runtime.h>

typedef __attribute__((ext_vector_type(8))) short bf16x8;
typedef __attribute__((ext_vector_type(4))) float f32x4;
typedef __attribute__((ext_vector_type(16))) float f32x16;

constexpr int T = 2048;
constexpr int D = 4096;
constexpr int NQ = 32;    // query heads
constexpr int NKV = 8;    // kv heads
constexpr int H = 128;    // head dim
constexpr int F = 14336;  // ffn dim
constexpr int NQKV = (NQ + 2 * NKV) * H;  // 6144 packed qkv cols
constexpr int VOFF = (NQ + NKV) * H;      // 5120 col offset of V

__device__ inline unsigned short f2bf(float f) {
  unsigned u = __float_as_uint(f);
  return (unsigned short)((u + 0x7FFFu + ((u >> 16) & 1u)) >> 16);
}

__device__ inline void gload_lds16(const void* g, void* l) {
  __builtin_amdgcn_global_load_lds((const __attribute__((address_space(1))) void*)g,
                                   (__attribute__((address_space(3))) void*)l, 16, 0, 0);
}

#define MFMA16(a, b, c) __builtin_amdgcn_mfma_f32_16x16x32_bf16(a, b, c, 0, 0, 0)
#define MFMA32(a, b, c) __builtin_amdgcn_mfma_f32_32x32x16_bf16(a, b, c, 0, 0, 0)

// ------- weight transpose+convert: (K,N) f32 -> (rowmap(N),K) bf16 -------
// MODE 0: row = n;  MODE 1: row = (n>>5)*64 + (n&31);  MODE 2: MODE1 + 32
template <int MODE>
__global__ __launch_bounds__(256) void transpose_bf16(const float* __restrict__ in,
                                                      unsigned short* __restrict__ out,
                                                      int K, int N) {
  __shared__ float tile[64 * 65];
  const int kb = blockIdx.x * 64;
  const int nb = blockIdx.y * 64;
  const int tid = threadIdx.x;
  const int r = tid >> 2;
  const int c4 = tid & 3;
#pragma unroll
  for (int i = 0; i < 4; ++i) {
    float4 v = *(const float4*)(in + (size_t)(kb + r) * N + nb + c4 * 16 + i * 4);
    *(float4*)&tile[r * 65 + c4 * 16 + i * 4] = v;
  }
  __syncthreads();
  const int n = tid >> 2;
  const int kq = tid & 3;
  int nsrc = nb + n;
  int prow = (MODE == 0) ? nsrc : ((nsrc >> 5) * 64 + (nsrc & 31) + (MODE == 2 ? 32 : 0));
#pragma unroll
  for (int half = 0; half < 2; ++half) {
    ushort4 o0, o1;
    int k0 = kq * 16 + half * 8;
    o0.x = f2bf(tile[(k0 + 0) * 65 + n]);
    o0.y = f2bf(tile[(k0 + 1) * 65 + n]);
    o0.z = f2bf(tile[(k0 + 2) * 65 + n]);
    o0.w = f2bf(tile[(k0 + 3) * 65 + n]);
    o1.x = f2bf(tile[(k0 + 4) * 65 + n]);
    o1.y = f2bf(tile[(k0 + 5) * 65 + n]);
    o1.z = f2bf(tile[(k0 + 6) * 65 + n]);
    o1.w = f2bf(tile[(k0 + 7) * 65 + n]);
    unsigned short* op = out + (size_t)prow * K + kb + k0;
    *(ushort4*)(op + 0) = o0;
    *(ushort4*)(op + 4) = o1;
  }
}

// ---------------- RMSNorm: f32 in -> bf16 out ----------------
__global__ __launch_bounds__(256) void rmsnorm_kernel(
    const float* __restrict__ in, const float* __restrict__ scale,
    unsigned short* __restrict__ out) {
  int row = blockIdx.x;
  const float4* xr = (const float4*)(in + (size_t)row * D);
  const float4* sr = (const float4*)scale;
  float4 vals[4];
  float ss = 0.f;
#pragma unroll
  for (int i = 0; i < 4; ++i) {
    float4 v = xr[threadIdx.x + i * 256];
    vals[i] = v;
    ss += v.x * v.x + v.y * v.y + v.z * v.z + v.w * v.w;
  }
#pragma unroll
  for (int off = 32; off; off >>= 1) ss += __shfl_xor(ss, off, 64);
  __shared__ float wsum[4];
  if ((threadIdx.x & 63) == 0) wsum[threadIdx.x >> 6] = ss;
  __syncthreads();
  float r = rsqrtf((wsum[0] + wsum[1] + wsum[2] + wsum[3]) * (1.f / D) + 1e-5f);
#pragma unroll
  for (int i = 0; i < 4; ++i) {
    int vi = threadIdx.x + i * 256;
    float4 v = vals[i];
    float4 s = sr[vi];
    ushort4 o;
    o.x = f2bf(v.x * r * s.x);
    o.y = f2bf(v.y * r * s.y);
    o.z = f2bf(v.z * r * s.z);
    o.w = f2bf(v.w * r * s.w);
    *(ushort4*)(out + (size_t)row * D + (size_t)vi * 4) = o;
  }
}

// ------- fused: resid = a+b+c (f32 out) ; h2 = rmsnorm(resid)*scale (bf16 out) -------
__global__ __launch_bounds__(256) void rmsnorm_add3(
    const float* __restrict__ a, const float* __restrict__ b,
    const float* __restrict__ c, const float* __restrict__ scale,
    float* __restrict__ residOut, unsigned short* __restrict__ out) {
  int row = blockIdx.x;
  const float4* ar = (const float4*)(a + (size_t)row * D);
  const float4* br = (const float4*)(b + (size_t)row * D);
  const float4* cr = (const float4*)(c + (size_t)row * D);
  const float4* sr = (const float4*)scale;
  float4* rr = (float4*)(residOut + (size_t)row * D);
  float4 vals[4];
  float ss = 0.f;
#pragma unroll
  for (int i = 0; i < 4; ++i) {
    int vi = threadIdx.x + i * 256;
    float4 va = ar[vi], vb = br[vi], vc = cr[vi];
    float4 v;
    v.x = va.x + vb.x + vc.x;
    v.y = va.y + vb.y + vc.y;
    v.z = va.z + vb.z + vc.z;
    v.w = va.w + vb.w + vc.w;
    vals[i] = v;
    ss += v.x * v.x + v.y * v.y + v.z * v.z + v.w * v.w;
  }
#pragma unroll
  for (int off = 32; off; off >>= 1) ss += __shfl_xor(ss, off, 64);
  __shared__ float wsum[4];
  if ((threadIdx.x & 63) == 0) wsum[threadIdx.x >> 6] = ss;
  __syncthreads();
  float r = rsqrtf((wsum[0] + wsum[1] + wsum[2] + wsum[3]) * (1.f / D) + 1e-5f);
#pragma unroll
  for (int i = 0; i < 4; ++i) {
    int vi = threadIdx.x + i * 256;
    float4 v = vals[i];
    rr[vi] = v;
    float4 s = sr[vi];
    ushort4 o;
    o.x = f2bf(v.x * r * s.x);
    o.y = f2bf(v.y * r * s.y);
    o.z = f2bf(v.z * r * s.z);
    o.w = f2bf(v.w * r * s.w);
    *(ushort4*)(out + (size_t)row * D + (size_t)vi * 4) = o;
  }
}

// ---------------- out = a + b + c (f32, vectorized) ----------------
__global__ __launch_bounds__(256) void add3_kernel(const float* __restrict__ a,
                                                   const float* __restrict__ b,
                                                   const float* __restrict__ c,
                                                   float* __restrict__ o) {
  int i = blockIdx.x * 256 + threadIdx.x;
  float4 va = ((const float4*)a)[i];
  float4 vb = ((const float4*)b)[i];
  float4 vc = ((const float4*)c)[i];
  float4 vo;
  vo.x = va.x + vb.x + vc.x;
  vo.y = va.y + vb.y + vc.y;
  vo.z = va.z + vb.z + vc.z;
  vo.w = va.w + vb.w + vc.w;
  ((float4*)o)[i] = vo;
}

// ---------------- RoPE cos/sin table ----------------
__global__ __launch_bounds__(256) void rope_table(const int* __restrict__ pos,
                                                  float* __restrict__ ctab,
                                                  float* __restrict__ stab) {
  int idx = blockIdx.x * 256 + threadIdx.x;  // T*64
  int t = idx >> 6, i = idx & 63;
  float inv = exp2f(-(float)i * (log2f(500000.0f) / 64.0f));
  float ang = (float)pos[t] * inv;
  ctab[idx] = cosf(ang);
  stab[idx] = sinf(ang);
}

// ------- RoPE apply: f32 strided in -> bf16 out (scale folded) -------
__global__ __launch_bounds__(256) void rope_bf16(const float* __restrict__ x,
                                                 const float* __restrict__ ctab,
                                                 const float* __restrict__ stab,
                                                 unsigned short* __restrict__ out,
                                                 int nheads, int row_stride, float scale) {
  int idx = blockIdx.x * 256 + threadIdx.x;  // T*nheads*64
  int i = idx & 63;
  int tn = idx >> 6;
  int t = tn / nheads;
  int n = tn - t * nheads;
  float c = ctab[t * 64 + i], s = stab[t * 64 + i];
  const float* p = x + (size_t)t * row_stride + n * H;
  float x1 = p[i], x2 = p[i + 64];
  unsigned short* o = out + (size_t)tn * H;
  o[i] = f2bf((x1 * c - x2 * s) * scale);
  o[i + 64] = f2bf((x2 * c + x1 * s) * scale);
}

// ---------------- 256x256 GEMM, 32x32x16 MFMA, single-barrier phases ----------------
// A (M,K) bf16; Bt (N,K) bf16. 8 waves (2M x 4N), per-wave 128x64 as 4x2 of 32x32.
// BK=64 (4 k-steps of 16). LDS 128KB dbuf; swizzle both sides byte_col ^= (row&7)<<4.
// Phase quadrants (2mf x 1nf x 4ks = 8 MFMA each) preserve the line-liveness
// invariants: A-lo read fully in P0 -> stage lines 0,2 in P1; B all-read by P1 ->
// stage B in P2 (+vmcnt(6)); A-hi read P2 -> stage lines 1,3 in P3.
// C/D map: col = lane&31, row = (r&3) + 8*(r>>2) + 4*(lane>>5).
// EP 0: outF/outF2 (by blockIdx.z) = acc (f32)
// EP 4: qkv: col<VOFF -> outF f32 stride Nd; else outB[(col-VOFF)*T+row] bf16
// EP 5: Bt packed gate/up alternating 32-col groups; outB = bf16(silu(g)*u)
template <int EP>
__global__ __launch_bounds__(512, 1) void gemm256(
    const unsigned short* __restrict__ A, const unsigned short* __restrict__ Bt,
    float* __restrict__ outF, float* __restrict__ outF2,
    unsigned short* __restrict__ outB, int Kd, int Nd, int Klen) {
  __shared__ unsigned short lds[65536];
  const int tid = threadIdx.x, lane = tid & 63, wv = tid >> 6;
  const int wm = wv >> 2, wn = wv & 3;
  const int r32 = lane & 31, h = lane >> 5;
  const int kz = blockIdx.z;
  // XCD-aware block swizzle within z-slice (gx*gy % 8 == 0)
  int raw = blockIdx.x + blockIdx.y * gridDim.x;
  int cpx = (gridDim.x * gridDim.y) >> 3;
  int sid = (raw & 7) * cpx + (raw >> 3);
  int brow = sid % gridDim.x;
  int bcol = sid / gridDim.x;
  const int m0 = brow * 256, n0 = bcol * 256;

  const int l8 = lane >> 3;
  const int scol = ((lane & 7) ^ l8) * 8;  // pre-swizzled global src col
  const int xr = (r32 & 7) << 4;           // read-side swizzle (row&7 == r32&7)
  int pc[4];
#pragma unroll
  for (int ks = 0; ks < 4; ++ks) pc[ks] = (ks * 32 + h * 16) ^ xr;

  const char* ldsc = (const char*)lds;
  const unsigned short* gA = A + (size_t)(m0 + wv * 8 + l8) * Kd + kz * Klen + scol;
  const unsigned short* gB = Bt + (size_t)(n0 + wv * 8 + l8) * Kd + kz * Klen + scol;

  f32x16 acc[4][2];
#pragma unroll
  for (int i = 0; i < 4; ++i)
#pragma unroll
    for (int j = 0; j < 2; ++j) acc[i][j] = (f32x16)(0.f);

  const int NT = Klen >> 6;

// line l covers tile rows [l*64, l*64+64): LDS ushort off l*4096 + wv*512
#define STAGE_AL(kt, l)                                                      \
  gload_lds16(gA + (size_t)(kt) * 64 + (size_t)(l) * 64 * Kd,                \
              (void*)&lds[((kt) & 1) * 32768 + (l) * 4096 + wv * 512]);
#define STAGE_BL(kt, l)                                                      \
  gload_lds16(gB + (size_t)(kt) * 64 + (size_t)(l) * 64 * Kd,                \
              (void*)&lds[((kt) & 1) * 32768 + 16384 + (l) * 4096 + wv * 512]);
#define SBAR()                        \
  __builtin_amdgcn_sched_barrier(0);  \
  __builtin_amdgcn_s_barrier();

  // prologue: stage kt=0 and kt=1 fully, drain kt=0's 8 lines
  STAGE_AL(0, 0); STAGE_AL(0, 1); STAGE_AL(0, 2); STAGE_AL(0, 3);
  STAGE_BL(0, 0); STAGE_BL(0, 1); STAGE_BL(0, 2); STAGE_BL(0, 3);
  STAGE_AL(1, 0); STAGE_AL(1, 1); STAGE_AL(1, 2); STAGE_AL(1, 3);
  STAGE_BL(1, 0); STAGE_BL(1, 1); STAGE_BL(1, 2); STAGE_BL(1, 3);
  asm volatile("s_waitcnt vmcnt(8)" ::: "memory");
  SBAR();

  // pre-read B nf0 of kt=0 (buffer 0)
  bf16x8 bLoC[4];
  {
    const char* bB0 = ldsc + 32768 + (wn * 64 + r32) * 128;
#pragma unroll
    for (int ks = 0; ks < 4; ++ks) bLoC[ks] = *(const bf16x8*)(bB0 + pc[ks]);
  }

  for (int kt = 0; kt < NT; ++kt) {
    const int b = kt & 1;
    const char* aB = ldsc + b * 65536 + (wm * 128 + r32) * 128;
    const char* bB = ldsc + b * 65536 + 32768 + (wn * 64 + r32) * 128;
    const char* bBn = ldsc + (b ^ 1) * 65536 + 32768 + (wn * 64 + r32) * 128;
    const bool pre = (kt + 2 < NT);
    bf16x8 aCur[2][4], aHi[2][4], bHi[4], bLoN[4];
    // ---- P0: read A mf0-1 (8); | q0 = aCur x bLoC ----
#pragma unroll
    for (int mp = 0; mp < 2; ++mp)
#pragma unroll
      for (int ks = 0; ks < 4; ++ks)
        aCur[mp][ks] = *(const bf16x8*)(aB + mp * 32 * 128 + pc[ks]);
    SBAR();
    __builtin_amdgcn_s_setprio(1);
#pragma unroll
    for (int mp = 0; mp < 2; ++mp)
#pragma unroll
      for (int ks = 0; ks < 4; ++ks)
        acc[mp][0] = MFMA32(aCur[mp][ks], bLoC[ks], acc[mp][0]);
    __builtin_amdgcn_s_setprio(0);
    // ---- P1: read B nf1 (4); stage A(kt+2) lines 0,2; | q1 ----
#pragma unroll
    for (int ks = 0; ks < 4; ++ks)
      bHi[ks] = *(const bf16x8*)(bB + 32 * 128 + pc[ks]);
    if (pre) { STAGE_AL(kt + 2, 0); STAGE_AL(kt + 2, 2); }
    SBAR();
    __builtin_amdgcn_s_setprio(1);
#pragma unroll
    for (int mp = 0; mp < 2; ++mp)
#pragma unroll
      for (int ks = 0; ks < 4; ++ks)
        acc[mp][1] = MFMA32(aCur[mp][ks], bHi[ks], acc[mp][1]);
    __builtin_amdgcn_s_setprio(0);
    // ---- P2: read A mf2-3 (8); stage B(kt+2) 4 lines; vmcnt; | q2 ----
#pragma unroll
    for (int mp = 0; mp < 2; ++mp)
#pragma unroll
      for (int ks = 0; ks < 4; ++ks)
        aHi[mp][ks] = *(const bf16x8*)(aB + (64 + mp * 32) * 128 + pc[ks]);
    if (pre) {
      STAGE_BL(kt + 2, 0); STAGE_BL(kt + 2, 1);
      STAGE_BL(kt + 2, 2); STAGE_BL(kt + 2, 3);
      asm volatile("s_waitcnt vmcnt(6)" ::: "memory");  // drain all kt+1 lines
    } else {
      asm volatile("s_waitcnt vmcnt(0)" ::: "memory");  // tail: drain everything
    }
    SBAR();
    __builtin_amdgcn_s_setprio(1);
#pragma unroll
    for (int mp = 0; mp < 2; ++mp)
#pragma unroll
      for (int ks = 0; ks < 4; ++ks)
        acc[2 + mp][1] = MFMA32(aHi[mp][ks], bHi[ks], acc[2 + mp][1]);
    __builtin_amdgcn_s_setprio(0);
    // ---- P3: stage A(kt+2) lines 1,3; pre-read B nf0(kt+1) (4); | q3 ----
    if (pre) { STAGE_AL(kt + 2, 1); STAGE_AL(kt + 2, 3); }
    if (kt + 1 < NT) {
#pragma unroll
      for (int ks = 0; ks < 4; ++ks) bLoN[ks] = *(const bf16x8*)(bBn + pc[ks]);
    }
    SBAR();
    __builtin_amdgcn_s_setprio(1);
#pragma unroll
    for (int mp = 0; mp < 2; ++mp)
#pragma unroll
      for (int ks = 0; ks < 4; ++ks)
        acc[2 + mp][0] = MFMA32(aHi[mp][ks], bLoC[ks], acc[2 + mp][0]);
    __builtin_amdgcn_s_setprio(0);
    if (kt + 1 < NT) {
#pragma unroll
      for (int ks = 0; ks < 4; ++ks) bLoC[ks] = bLoN[ks];
    }
  }

  // epilogue; C map: col = r32, rowoff(r) = (r&3) + 8*(r>>2) + 4*h
  if constexpr (EP == 5) {
    const int acol = ((n0 + wn * 64) >> 1) + r32;
#pragma unroll
    for (int mf = 0; mf < 4; ++mf) {
      int rowb = m0 + wm * 128 + mf * 32 + 4 * h;
#pragma unroll
      for (int r = 0; r < 16; ++r) {
        int row = rowb + (r & 3) + 8 * (r >> 2);
        float gg = acc[mf][0][r];
        float uu = acc[mf][1][r];
        outB[(size_t)row * F + acol] = f2bf(gg / (1.f + __expf(-gg)) * uu);
      }
    }
  } else if constexpr (EP == 4) {
    if (n0 >= VOFF) {
#pragma unroll
      for (int mf = 0; mf < 4; ++mf)
#pragma unroll
        for (int nf = 0; nf < 2; ++nf) {
          int col = n0 + wn * 64 + nf * 32 + r32;
          int rowb = m0 + wm * 128 + mf * 32 + 4 * h;
#pragma unroll
          for (int q = 0; q < 4; ++q) {
            ushort4 o;
            o.x = f2bf(acc[mf][nf][q * 4 + 0]);
            o.y = f2bf(acc[mf][nf][q * 4 + 1]);
            o.z = f2bf(acc[mf][nf][q * 4 + 2]);
            o.w = f2bf(acc[mf][nf][q * 4 + 3]);
            *(ushort4*)&outB[(size_t)(col - VOFF) * T + rowb + 8 * q] = o;
          }
        }
    } else {
#pragma unroll
      for (int mf = 0; mf < 4; ++mf)
#pragma unroll
        for (int nf = 0; nf < 2; ++nf) {
          int col = n0 + wn * 64 + nf * 32 + r32;
          int rowb = m0 + wm * 128 + mf * 32 + 4 * h;
#pragma unroll
          for (int r = 0; r < 16; ++r)
            outF[(size_t)(rowb + (r & 3) + 8 * (r >> 2)) * Nd + col] = acc[mf][nf][r];
        }
    }
  } else {
    float* dst = kz ? outF2 : outF;
#pragma unroll
    for (int mf = 0; mf < 4; ++mf)
#pragma unroll
      for (int nf = 0; nf < 2; ++nf) {
        int col = n0 + wn * 64 + nf * 32 + r32;
        int rowb = m0 + wm * 128 + mf * 32 + 4 * h;
#pragma unroll
        for (int r = 0; r < 16; ++r)
          dst[(size_t)(rowb + (r & 3) + 8 * (r >> 2)) * Nd + col] = acc[mf][nf][r];
      }
  }
#undef STAGE_AL
#undef STAGE_BL
#undef SBAR
}

// ---------------- Flash attention (MFMA), GQA group-shared K/V, T14 dbuf ----------------
constexpr int KLD = 136;
constexpr int VLD = 72;
constexpr int PLD = 72;

__global__ __launch_bounds__(512) void flash_attn(
    const unsigned short* __restrict__ qbf, const unsigned short* __restrict__ kbf,
    const unsigned short* __restrict__ vtbf, unsigned short* __restrict__ out) {
  __shared__ unsigned short K_lds[64 * KLD];
  __shared__ unsigned short Vt_lds[H * VLD];
  __shared__ unsigned short P_lds[8 * 16 * PLD];

  const int tid = threadIdx.x;
  const int lane = tid & 63;
  const int wv = tid >> 6;
  const int qb = blockIdx.x;   // 32-row q block
  const int kvh = blockIdx.y;  // kv head
  const int qh = wv & 3, rh = wv >> 2;
  const int n = kvh * 4 + qh;
  const int g = lane >> 4;
  const int rl = lane & 15;
  const int qrow = qb * 32 + rh * 16;

  bf16x8 qfrag[4];
  {
    const unsigned short* qp = qbf + ((size_t)(qrow + rl) * NQ + n) * H + g * 8;
#pragma unroll
    for (int ks = 0; ks < 4; ++ks) qfrag[ks] = *(const bf16x8*)(qp + ks * 32);
  }

  f32x4 oacc[8];
#pragma unroll
  for (int ob = 0; ob < 8; ++ob) oacc[ob] = (f32x4){0.f, 0.f, 0.f, 0.f};
  float mrun[4] = {-1e30f, -1e30f, -1e30f, -1e30f};
  float lrun[4] = {0.f, 0.f, 0.f, 0.f};

  // staging maps (512 threads): K 64x128, Vt 128x64, 16 cols/thread each
  const int krow = tid >> 3, kseg = (tid & 7) * 16;
  const int vh = tid >> 2, vseg = (tid & 3) * 16;

  const int ktmax = (qb * 32 + 31) >> 6;
  // T14: preload tile 0 into regs; per-tile {write LDS; issue next loads; compute}
  bf16x8 krA, krB, vrA, vrB;
  {
    const unsigned short* kp = kbf + ((size_t)krow * NKV + kvh) * H + kseg;
    krA = *(const bf16x8*)kp;
    krB = *(const bf16x8*)(kp + 8);
    const unsigned short* vp = vtbf + (size_t)(kvh * H + vh) * T + vseg;
    vrA = *(const bf16x8*)vp;
    vrB = *(const bf16x8*)(vp + 8);
  }
  for (int kt = 0; kt <= ktmax; ++kt) {
    const int kbase = kt * 64;
    __syncthreads();  // previous tile's readers done
    *(bf16x8*)&K_lds[krow * KLD + kseg] = krA;
    *(bf16x8*)&K_lds[krow * KLD + kseg + 8] = krB;
    *(bf16x8*)&Vt_lds[vh * VLD + vseg] = vrA;
    *(bf16x8*)&Vt_lds[vh * VLD + vseg + 8] = vrB;
    if (kt < ktmax) {  // issue next-tile loads; land under this tile's compute
      const unsigned short* kp =
          kbf + ((size_t)(kbase + 64 + krow) * NKV + kvh) * H + kseg;
      krA = *(const bf16x8*)kp;
      krB = *(const bf16x8*)(kp + 8);
      const unsigned short* vp =
          vtbf + (size_t)(kvh * H + vh) * T + kbase + 64 + vseg;
      vrA = *(const bf16x8*)vp;
      vrB = *(const bf16x8*)(vp + 8);
    }
    __syncthreads();

    f32x4 sacc[4];
#pragma unroll
    for (int cb = 0; cb < 4; ++cb) sacc[cb] = (f32x4){0.f, 0.f, 0.f, 0.f};
#pragma unroll
    for (int cb = 0; cb < 4; ++cb)
#pragma unroll
      for (int ks = 0; ks < 4; ++ks) {
        bf16x8 kf = *(const bf16x8*)&K_lds[(cb * 16 + rl) * KLD + ks * 32 + g * 8];
        sacc[cb] = MFMA16(qfrag[ks], kf, sacc[cb]);
      }

    if (kt == ktmax) {  // causal mask, absolute indices
#pragma unroll
      for (int cb = 0; cb < 4; ++cb) {
        int kv_abs = kbase + cb * 16 + rl;
#pragma unroll
        for (int r = 0; r < 4; ++r) {
          if (kv_abs > qrow + g * 4 + r) sacc[cb][r] = -1e30f;
        }
      }
    }

    float mx[4], sm[4], corr[4];
#pragma unroll
    for (int r = 0; r < 4; ++r) {
      float m0 = fmaxf(fmaxf(sacc[0][r], sacc[1][r]), fmaxf(sacc[2][r], sacc[3][r]));
#pragma unroll
      for (int off = 1; off < 16; off <<= 1) m0 = fmaxf(m0, __shfl_xor(m0, off, 64));
      float nm = fmaxf(mrun[r], m0);
      corr[r] = __expf(mrun[r] - nm);
      mrun[r] = nm;
      mx[r] = nm;
    }
#pragma unroll
    for (int cb = 0; cb < 4; ++cb)
#pragma unroll
      for (int r = 0; r < 4; ++r) sacc[cb][r] = __expf(sacc[cb][r] - mx[r]);
#pragma unroll
    for (int r = 0; r < 4; ++r) {
      float s0 = sacc[0][r] + sacc[1][r] + sacc[2][r] + sacc[3][r];
#pragma unroll
      for (int off = 1; off < 16; off <<= 1) s0 += __shfl_xor(s0, off, 64);
      sm[r] = s0;
      lrun[r] = lrun[r] * corr[r] + sm[r];
    }
#pragma unroll
    for (int ob = 0; ob < 8; ++ob)
#pragma unroll
      for (int r = 0; r < 4; ++r) oacc[ob][r] *= corr[r];

#pragma unroll
    for (int cb = 0; cb < 4; ++cb)
#pragma unroll
      for (int r = 0; r < 4; ++r)
        P_lds[(wv * 16 + g * 4 + r) * PLD + cb * 16 + rl] = f2bf(sacc[cb][r]);

    bf16x8 pa[2];
#pragma unroll
    for (int ks = 0; ks < 2; ++ks)
      pa[ks] = *(const bf16x8*)&P_lds[(wv * 16 + rl) * PLD + ks * 32 + g * 8];

#pragma unroll
    for (int ob = 0; ob < 8; ++ob)
#pragma unroll
      for (int ks = 0; ks < 2; ++ks) {
        bf16x8 vf = *(const bf16x8*)&Vt_lds[(ob * 16 + rl) * VLD + ks * 32 + g * 8];
        oacc[ob] = MFMA16(pa[ks], vf, oacc[ob]);
      }
  }

  float inv[4];
#pragma unroll
  for (int r = 0; r < 4; ++r) inv[r] = 1.f / lrun[r];
#pragma unroll
  for (int ob = 0; ob < 8; ++ob)
#pragma unroll
    for (int r = 0; r < 4; ++r) {
      int t = qrow + g * 4 + r;
      out[((size_t)t * NQ + n) * H + ob * 16 + rl] = f2bf(oacc[ob][r] * inv[r]);
    }
}

extern "C" void kernel_launch(void* const* d_in, const int* in_sizes, int n_in,
                              void* d_out, int out_size, void* d_ws, size_t ws_size,
                              hipStream_t stream) {
  (void)in_sizes; (void)n_in; (void)out_size; (void)ws_size;
  const float* x = (const float*)d_in[0];
  const int* positions = (const int*)d_in[1];
  const float* ln1 = (const float*)d_in[2];
  const float* w_q = (const float*)d_in[3];
  const float* w_k = (const float*)d_in[4];
  const float* w_v = (const float*)d_in[5];
  const float* w_o = (const float*)d_in[6];
  const float* ln2 = (const float*)d_in[7];
  const float* w_gate = (const float*)d_in[8];
  const float* w_up = (const float*)d_in[9];
  const float* w_down = (const float*)d_in[10];
  float* out = (float*)d_out;

  char* ws = (char*)d_ws;
  size_t off = 0;
  auto alloc = [&](size_t bytes) {
    char* p = ws + off;
    off += (bytes + 255) & ~(size_t)255;
    return p;
  };
  unsigned short* h_bf = (unsigned short*)alloc((size_t)T * D * 2);
  unsigned short* h2_bf = (unsigned short*)alloc((size_t)T * D * 2);
  unsigned short* attn_bf = (unsigned short*)alloc((size_t)T * NQ * H * 2);
  unsigned short* act_bf = (unsigned short*)alloc((size_t)T * F * 2);
  float* qkvf = (float*)alloc((size_t)T * NQKV * 4);
  float* resid = (float*)alloc((size_t)T * D * 4);
  float* ctab = (float*)alloc((size_t)T * 64 * 4);
  float* stab = (float*)alloc((size_t)T * 64 * 4);
  unsigned short* qbf = (unsigned short*)alloc((size_t)T * NQ * H * 2);
  unsigned short* kbf = (unsigned short*)alloc((size_t)T * NKV * H * 2);
  unsigned short* vtbf = (unsigned short*)alloc((size_t)NKV * H * T * 2);
  unsigned short* wqkvt = (unsigned short*)alloc((size_t)NQKV * D * 2);
  unsigned short* wot = (unsigned short*)alloc((size_t)D * NQ * H * 2);
  unsigned short* wgut = (unsigned short*)alloc((size_t)2 * F * D * 2);
  unsigned short* wdt = (unsigned short*)alloc((size_t)D * F * 2);
  // K-split partial buffers aliased onto dead regions (each needs T*D*4 = 33.6MB)
  float* part0 = qkvf;            // qkvf: 50.3MB, dead after rope_bf16
  float* part1 = (float*)wqkvt;   // wqkvt: 50.3MB, dead after QKV GEMM

  transpose_bf16<0><<<dim3(D / 64, (NQ * H) / 64), 256, 0, stream>>>(w_q, wqkvt, D, NQ * H);
  transpose_bf16<0><<<dim3(D / 64, (NKV * H) / 64), 256, 0, stream>>>(
      w_k, wqkvt + (size_t)NQ * H * D, D, NKV * H);
  transpose_bf16<0><<<dim3(D / 64, (NKV * H) / 64), 256, 0, stream>>>(
      w_v, wqkvt + (size_t)VOFF * D, D, NKV * H);
  transpose_bf16<0><<<dim3((NQ * H) / 64, D / 64), 256, 0, stream>>>(w_o, wot, NQ * H, D);
  transpose_bf16<1><<<dim3(D / 64, F / 64), 256, 0, stream>>>(w_gate, wgut, D, F);
  transpose_bf16<2><<<dim3(D / 64, F / 64), 256, 0, stream>>>(w_up, wgut, D, F);
  transpose_bf16<0><<<dim3(F / 64, D / 64), 256, 0, stream>>>(w_down, wdt, F, D);

  rmsnorm_kernel<<<T, 256, 0, stream>>>(x, ln1, h_bf);
  rope_table<<<(T * 64) / 256, 256, 0, stream>>>(positions, ctab, stab);
  // QKV on 256² structure: q/k -> qkvf f32, V -> vtbf bf16 transposed
  gemm256<4><<<dim3(T / 256, NQKV / 256, 1), 512, 0, stream>>>(
      h_bf, wqkvt, qkvf, nullptr, vtbf, D, NQKV, D);
  rope_bf16<<<(T * NQ * 64) / 256, 256, 0, stream>>>(qkvf, ctab, stab, qbf, NQ, NQKV,
                                                     0.08838834764831845f);
  rope_bf16<<<(T * NKV * 64) / 256, 256, 0, stream>>>(qkvf + NQ * H, ctab, stab, kbf,
                                                      NKV, NQKV, 1.0f);
  flash_attn<<<dim3(T / 32, NKV), 512, 0, stream>>>(qbf, kbf, vtbf, attn_bf);
  // O-proj: 256² K-split x2 (full machine) -> partials
  gemm256<0><<<dim3(T / 256, D / 256, 2), 512, 0, stream>>>(
      attn_bf, wot, part0, part1, nullptr, NQ * H, D, NQ * H / 2);
  // fused: resid = p0+p1+x ; h2 = rmsnorm(resid)*ln2
  rmsnorm_add3<<<T, 256, 0, stream>>>(part0, part1, x, ln2, resid, h2_bf);
  // 256² interleaved gate/up GEMM
  gemm256<5><<<dim3(T / 256, (2 * F) / 256), 512, 0, stream>>>(
      h2_bf, wgut, nullptr, nullptr, act_bf, D, 2 * F, D);
  // down-proj: 256² K-split x2 -> partials, then out = p0+p1+resid
  gemm256<0><<<dim3(T / 256, D / 256, 2), 512, 0, stream>>>(
      act_bf, wdt, part0, part1, nullptr, F, D, F / 2);
  add3_kernel<<<(T * D / 4) / 256, 256, 0, stream>>>(part0, part1, resid, out);
}

// Round 13
// 1330.921 us; speedup vs baseline: 1.0265x; 1.0265x over previous
//
#include <hip/hip_runtime.h>

typedef __attribute__((ext_vector_type(8))) short bf16x8;
typedef __attribute__((ext_vector_type(4))) float f32x4;

constexpr int T = 2048;
constexpr int D = 4096;
constexpr int NQ = 32;    // query heads
constexpr int NKV = 8;    // kv heads
constexpr int H = 128;    // head dim
constexpr int F = 14336;  // ffn dim
constexpr int NQKV = (NQ + 2 * NKV) * H;  // 6144 packed qkv cols
constexpr int VOFF = (NQ + NKV) * H;      // 5120 col offset of V

__device__ inline unsigned short f2bf(float f) {
  unsigned u = __float_as_uint(f);
  return (unsigned short)((u + 0x7FFFu + ((u >> 16) & 1u)) >> 16);
}

__device__ inline void gload_lds16(const void* g, void* l) {
  __builtin_amdgcn_global_load_lds((const __attribute__((address_space(1))) void*)g,
                                   (__attribute__((address_space(3))) void*)l, 16, 0, 0);
}

#define MFMA16(a, b, c) __builtin_amdgcn_mfma_f32_16x16x32_bf16(a, b, c, 0, 0, 0)

// ------- weight transpose+convert: (K,N) f32 -> (rowmap(N),K) bf16 -------
// MODE 0: row = n;  MODE 1: row = (n>>4)*32 + (n&15);  MODE 2: MODE1 + 16
template <int MODE>
__global__ __launch_bounds__(256) void transpose_bf16(const float* __restrict__ in,
                                                      unsigned short* __restrict__ out,
                                                      int K, int N) {
  __shared__ float tile[64 * 65];
  const int kb = blockIdx.x * 64;
  const int nb = blockIdx.y * 64;
  const int tid = threadIdx.x;
  const int r = tid >> 2;
  const int c4 = tid & 3;
#pragma unroll
  for (int i = 0; i < 4; ++i) {
    float4 v = *(const float4*)(in + (size_t)(kb + r) * N + nb + c4 * 16 + i * 4);
    *(float4*)&tile[r * 65 + c4 * 16 + i * 4] = v;
  }
  __syncthreads();
  const int n = tid >> 2;
  const int kq = tid & 3;
  int nsrc = nb + n;
  int prow = (MODE == 0) ? nsrc : ((nsrc >> 4) * 32 + (nsrc & 15) + (MODE == 2 ? 16 : 0));
#pragma unroll
  for (int half = 0; half < 2; ++half) {
    ushort4 o0, o1;
    int k0 = kq * 16 + half * 8;
    o0.x = f2bf(tile[(k0 + 0) * 65 + n]);
    o0.y = f2bf(tile[(k0 + 1) * 65 + n]);
    o0.z = f2bf(tile[(k0 + 2) * 65 + n]);
    o0.w = f2bf(tile[(k0 + 3) * 65 + n]);
    o1.x = f2bf(tile[(k0 + 4) * 65 + n]);
    o1.y = f2bf(tile[(k0 + 5) * 65 + n]);
    o1.z = f2bf(tile[(k0 + 6) * 65 + n]);
    o1.w = f2bf(tile[(k0 + 7) * 65 + n]);
    unsigned short* op = out + (size_t)prow * K + kb + k0;
    *(ushort4*)(op + 0) = o0;
    *(ushort4*)(op + 4) = o1;
  }
}

// ---------------- RMSNorm: f32 in -> bf16 out ----------------
__global__ __launch_bounds__(256) void rmsnorm_kernel(
    const float* __restrict__ in, const float* __restrict__ scale,
    unsigned short* __restrict__ out) {
  int row = blockIdx.x;
  const float4* xr = (const float4*)(in + (size_t)row * D);
  const float4* sr = (const float4*)scale;
  float4 vals[4];
  float ss = 0.f;
#pragma unroll
  for (int i = 0; i < 4; ++i) {
    float4 v = xr[threadIdx.x + i * 256];
    vals[i] = v;
    ss += v.x * v.x + v.y * v.y + v.z * v.z + v.w * v.w;
  }
#pragma unroll
  for (int off = 32; off; off >>= 1) ss += __shfl_xor(ss, off, 64);
  __shared__ float wsum[4];
  if ((threadIdx.x & 63) == 0) wsum[threadIdx.x >> 6] = ss;
  __syncthreads();
  float r = rsqrtf((wsum[0] + wsum[1] + wsum[2] + wsum[3]) * (1.f / D) + 1e-5f);
#pragma unroll
  for (int i = 0; i < 4; ++i) {
    int vi = threadIdx.x + i * 256;
    float4 v = vals[i];
    float4 s = sr[vi];
    ushort4 o;
    o.x = f2bf(v.x * r * s.x);
    o.y = f2bf(v.y * r * s.y);
    o.z = f2bf(v.z * r * s.z);
    o.w = f2bf(v.w * r * s.w);
    *(ushort4*)(out + (size_t)row * D + (size_t)vi * 4) = o;
  }
}

// ------- fused: resid = a+b+c (f32 out) ; h2 = rmsnorm(resid)*scale (bf16 out) -------
__global__ __launch_bounds__(256) void rmsnorm_add3(
    const float* __restrict__ a, const float* __restrict__ b,
    const float* __restrict__ c, const float* __restrict__ scale,
    float* __restrict__ residOut, unsigned short* __restrict__ out) {
  int row = blockIdx.x;
  const float4* ar = (const float4*)(a + (size_t)row * D);
  const float4* br = (const float4*)(b + (size_t)row * D);
  const float4* cr = (const float4*)(c + (size_t)row * D);
  const float4* sr = (const float4*)scale;
  float4* rr = (float4*)(residOut + (size_t)row * D);
  float4 vals[4];
  float ss = 0.f;
#pragma unroll
  for (int i = 0; i < 4; ++i) {
    int vi = threadIdx.x + i * 256;
    float4 va = ar[vi], vb = br[vi], vc = cr[vi];
    float4 v;
    v.x = va.x + vb.x + vc.x;
    v.y = va.y + vb.y + vc.y;
    v.z = va.z + vb.z + vc.z;
    v.w = va.w + vb.w + vc.w;
    vals[i] = v;
    ss += v.x * v.x + v.y * v.y + v.z * v.z + v.w * v.w;
  }
#pragma unroll
  for (int off = 32; off; off >>= 1) ss += __shfl_xor(ss, off, 64);
  __shared__ float wsum[4];
  if ((threadIdx.x & 63) == 0) wsum[threadIdx.x >> 6] = ss;
  __syncthreads();
  float r = rsqrtf((wsum[0] + wsum[1] + wsum[2] + wsum[3]) * (1.f / D) + 1e-5f);
#pragma unroll
  for (int i = 0; i < 4; ++i) {
    int vi = threadIdx.x + i * 256;
    float4 v = vals[i];
    rr[vi] = v;
    float4 s = sr[vi];
    ushort4 o;
    o.x = f2bf(v.x * r * s.x);
    o.y = f2bf(v.y * r * s.y);
    o.z = f2bf(v.z * r * s.z);
    o.w = f2bf(v.w * r * s.w);
    *(ushort4*)(out + (size_t)row * D + (size_t)vi * 4) = o;
  }
}

// ---------------- out = a + b + c (f32, vectorized) ----------------
__global__ __launch_bounds__(256) void add3_kernel(const float* __restrict__ a,
                                                   const float* __restrict__ b,
                                                   const float* __restrict__ c,
                                                   float* __restrict__ o) {
  int i = blockIdx.x * 256 + threadIdx.x;
  float4 va = ((const float4*)a)[i];
  float4 vb = ((const float4*)b)[i];
  float4 vc = ((const float4*)c)[i];
  float4 vo;
  vo.x = va.x + vb.x + vc.x;
  vo.y = va.y + vb.y + vc.y;
  vo.z = va.z + vb.z + vc.z;
  vo.w = va.w + vb.w + vc.w;
  ((float4*)o)[i] = vo;
}

// ---------------- RoPE cos/sin table ----------------
__global__ __launch_bounds__(256) void rope_table(const int* __restrict__ pos,
                                                  float* __restrict__ ctab,
                                                  float* __restrict__ stab) {
  int idx = blockIdx.x * 256 + threadIdx.x;  // T*64
  int t = idx >> 6, i = idx & 63;
  float inv = exp2f(-(float)i * (log2f(500000.0f) / 64.0f));
  float ang = (float)pos[t] * inv;
  ctab[idx] = cosf(ang);
  stab[idx] = sinf(ang);
}

// ------- RoPE apply: f32 strided in -> bf16 out (scale folded) -------
__global__ __launch_bounds__(256) void rope_bf16(const float* __restrict__ x,
                                                 const float* __restrict__ ctab,
                                                 const float* __restrict__ stab,
                                                 unsigned short* __restrict__ out,
                                                 int nheads, int row_stride, float scale) {
  int idx = blockIdx.x * 256 + threadIdx.x;  // T*nheads*64
  int i = idx & 63;
  int tn = idx >> 6;
  int t = tn / nheads;
  int n = tn - t * nheads;
  float c = ctab[t * 64 + i], s = stab[t * 64 + i];
  const float* p = x + (size_t)t * row_stride + n * H;
  float x1 = p[i], x2 = p[i + 64];
  unsigned short* o = out + (size_t)tn * H;
  o[i] = f2bf((x1 * c - x2 * s) * scale);
  o[i + 64] = f2bf((x2 * c + x1 * s) * scale);
}

// ---------------- 256x256 GEMM, 2-barrier R/C schedule, K-splittable ----------------
// A (M,K) bf16; Bt (N,K) bf16. 8 waves (2M x 4N), per-wave 128x64. BK=64.
// LDS 128KB dbuf. Swizzle both sides: byte_col ^= (row&7)<<4 (16x16 frag map,
// measured conflict-free). Per K-tile: R = read ALL 24 fragments (A16+B8, ~96
// extra VGPR) | barrier | C = stage kt+2 (issued first; lands under MFMA),
// 64-MFMA burst, vmcnt(8) (drains kt+1, kt+2 stays in flight) | barrier.
// Stage target buffer (kt+2 ≡ kt mod 2) is read only in R, fully before the
// barrier -> single-barrier separation is safe.
// EP 0: outF/outF2 (by blockIdx.z) = acc (f32)
// EP 4: qkv: col<VOFF -> outF f32 stride Nd; else outB[(col-VOFF)*T+row] bf16
// EP 5: Bt packed gate/up alternating 16-col groups; outB = bf16(silu(g)*u)
template <int EP>
__global__ __launch_bounds__(512, 1) void gemm256(
    const unsigned short* __restrict__ A, const unsigned short* __restrict__ Bt,
    float* __restrict__ outF, float* __restrict__ outF2,
    unsigned short* __restrict__ outB, int Kd, int Nd, int Klen) {
  __shared__ unsigned short lds[65536];
  const int tid = threadIdx.x, lane = tid & 63, wv = tid >> 6;
  const int wm = wv >> 2, wn = wv & 3;
  const int rl = lane & 15, g = lane >> 4;
  const int kz = blockIdx.z;
  // XCD-aware block swizzle within z-slice (gx*gy % 8 == 0)
  int raw = blockIdx.x + blockIdx.y * gridDim.x;
  int cpx = (gridDim.x * gridDim.y) >> 3;
  int sid = (raw & 7) * cpx + (raw >> 3);
  int brow = sid % gridDim.x;
  int bcol = sid / gridDim.x;
  const int m0 = brow * 256, n0 = bcol * 256;

  const int l8 = lane >> 3;
  const int scol = ((lane & 7) ^ l8) * 8;  // pre-swizzled global src col
  const int xr = (rl & 7) << 4;            // read-side swizzle
  const int pc0 = (g * 16) ^ xr;
  const int pc1 = (64 + g * 16) ^ xr;

  const char* ldsc = (const char*)lds;
  const unsigned short* gA = A + (size_t)(m0 + wv * 8 + l8) * Kd + kz * Klen + scol;
  const unsigned short* gB = Bt + (size_t)(n0 + wv * 8 + l8) * Kd + kz * Klen + scol;

  f32x4 acc[8][4];
#pragma unroll
  for (int i = 0; i < 8; ++i)
#pragma unroll
    for (int j = 0; j < 4; ++j) acc[i][j] = (f32x4){0.f, 0.f, 0.f, 0.f};

  const int NT = Klen >> 6;

// line l covers tile rows [l*64, l*64+64): LDS ushort off l*4096 + wv*512
#define STAGE_AL(kt, l)                                                      \
  gload_lds16(gA + (size_t)(kt) * 64 + (size_t)(l) * 64 * Kd,                \
              (void*)&lds[((kt) & 1) * 32768 + (l) * 4096 + wv * 512]);
#define STAGE_BL(kt, l)                                                      \
  gload_lds16(gB + (size_t)(kt) * 64 + (size_t)(l) * 64 * Kd,                \
              (void*)&lds[((kt) & 1) * 32768 + 16384 + (l) * 4096 + wv * 512]);
#define SBAR()                        \
  __builtin_amdgcn_sched_barrier(0);  \
  __builtin_amdgcn_s_barrier();

  // prologue: stage kt=0 and kt=1 fully, drain kt=0's 8 lines
  STAGE_AL(0, 0); STAGE_AL(0, 1); STAGE_AL(0, 2); STAGE_AL(0, 3);
  STAGE_BL(0, 0); STAGE_BL(0, 1); STAGE_BL(0, 2); STAGE_BL(0, 3);
  STAGE_AL(1, 0); STAGE_AL(1, 1); STAGE_AL(1, 2); STAGE_AL(1, 3);
  STAGE_BL(1, 0); STAGE_BL(1, 1); STAGE_BL(1, 2); STAGE_BL(1, 3);
  asm volatile("s_waitcnt vmcnt(8)" ::: "memory");
  SBAR();

  const int bhalf = (wn >> 1) * 16384;
  const int brl = (wn & 1) * 64;

  for (int kt = 0; kt < NT; ++kt) {
    const int b = kt & 1;
    const char* aB = ldsc + b * 65536 + wm * 16384;
    const char* bB = ldsc + b * 65536 + 32768 + bhalf;
    const bool pre = (kt + 2 < NT);
    bf16x8 aR[8][2], bR[4][2];
    // ---- R: read all fragments of kt ----
#pragma unroll
    for (int mf = 0; mf < 8; ++mf) {
      aR[mf][0] = *(const bf16x8*)(aB + (mf * 16 + rl) * 128 + pc0);
      aR[mf][1] = *(const bf16x8*)(aB + (mf * 16 + rl) * 128 + pc1);
    }
#pragma unroll
    for (int nf = 0; nf < 4; ++nf) {
      bR[nf][0] = *(const bf16x8*)(bB + (brl + nf * 16 + rl) * 128 + pc0);
      bR[nf][1] = *(const bf16x8*)(bB + (brl + nf * 16 + rl) * 128 + pc1);
    }
    SBAR();
    // ---- C: stage kt+2 first (lands under MFMA), then 64-MFMA burst ----
    if (pre) {
      STAGE_AL(kt + 2, 0); STAGE_AL(kt + 2, 1);
      STAGE_AL(kt + 2, 2); STAGE_AL(kt + 2, 3);
      STAGE_BL(kt + 2, 0); STAGE_BL(kt + 2, 1);
      STAGE_BL(kt + 2, 2); STAGE_BL(kt + 2, 3);
    }
    __builtin_amdgcn_s_setprio(1);
#pragma unroll
    for (int mf = 0; mf < 8; ++mf)
#pragma unroll
      for (int nf = 0; nf < 4; ++nf) {
        acc[mf][nf] = MFMA16(aR[mf][0], bR[nf][0], acc[mf][nf]);
        acc[mf][nf] = MFMA16(aR[mf][1], bR[nf][1], acc[mf][nf]);
      }
    __builtin_amdgcn_s_setprio(0);
    if (pre) {
      asm volatile("s_waitcnt vmcnt(8)" ::: "memory");  // kt+1 landed; kt+2 in flight
    } else if (kt + 1 < NT) {
      asm volatile("s_waitcnt vmcnt(0)" ::: "memory");  // tail: drain everything
    }
    SBAR();
  }

  const int g4 = g * 4;
  if constexpr (EP == 5) {
    const int acolBase = ((n0 + wn * 64) >> 1) + rl;
#pragma unroll
    for (int mf = 0; mf < 8; ++mf)
#pragma unroll
      for (int p = 0; p < 2; ++p) {
        int acol = acolBase + p * 16;
#pragma unroll
        for (int jj = 0; jj < 4; ++jj) {
          int row = m0 + wm * 128 + mf * 16 + g4 + jj;
          float gg = acc[mf][2 * p][jj];
          float uu = acc[mf][2 * p + 1][jj];
          outB[(size_t)row * F + acol] = f2bf(gg / (1.f + __expf(-gg)) * uu);
        }
      }
  } else if constexpr (EP == 4) {
    if (n0 >= VOFF) {
      // V region: bf16 transposed (NKV*H, T)
#pragma unroll
      for (int mf = 0; mf < 8; ++mf)
#pragma unroll
        for (int q = 0; q < 4; ++q) {
          int col = n0 + wn * 64 + q * 16 + rl;
          int row0 = m0 + wm * 128 + mf * 16 + g4;
          ushort4 o;
          o.x = f2bf(acc[mf][q][0]);
          o.y = f2bf(acc[mf][q][1]);
          o.z = f2bf(acc[mf][q][2]);
          o.w = f2bf(acc[mf][q][3]);
          *(ushort4*)&outB[(size_t)(col - VOFF) * T + row0] = o;
        }
    } else {
#pragma unroll
      for (int mf = 0; mf < 8; ++mf)
#pragma unroll
        for (int q = 0; q < 4; ++q) {
          int col = n0 + wn * 64 + q * 16 + rl;
#pragma unroll
          for (int jj = 0; jj < 4; ++jj) {
            int row = m0 + wm * 128 + mf * 16 + g4 + jj;
            outF[(size_t)row * Nd + col] = acc[mf][q][jj];
          }
        }
    }
  } else {
    float* dst = kz ? outF2 : outF;
#pragma unroll
    for (int mf = 0; mf < 8; ++mf)
#pragma unroll
      for (int q = 0; q < 4; ++q) {
        int col = n0 + wn * 64 + q * 16 + rl;
#pragma unroll
        for (int jj = 0; jj < 4; ++jj) {
          int row = m0 + wm * 128 + mf * 16 + g4 + jj;
          dst[(size_t)row * Nd + col] = acc[mf][q][jj];
        }
      }
  }
#undef STAGE_AL
#undef STAGE_BL
#undef SBAR
}

// ---------------- Flash attention (MFMA), GQA group-shared K/V, T14 dbuf ----------------
constexpr int KLD = 136;
constexpr int VLD = 72;
constexpr int PLD = 72;

__global__ __launch_bounds__(512) void flash_attn(
    const unsigned short* __restrict__ qbf, const unsigned short* __restrict__ kbf,
    const unsigned short* __restrict__ vtbf, unsigned short* __restrict__ out) {
  __shared__ unsigned short K_lds[64 * KLD];
  __shared__ unsigned short Vt_lds[H * VLD];
  __shared__ unsigned short P_lds[8 * 16 * PLD];

  const int tid = threadIdx.x;
  const int lane = tid & 63;
  const int wv = tid >> 6;
  const int qb = blockIdx.x;   // 32-row q block
  const int kvh = blockIdx.y;  // kv head
  const int qh = wv & 3, rh = wv >> 2;
  const int n = kvh * 4 + qh;
  const int g = lane >> 4;
  const int rl = lane & 15;
  const int qrow = qb * 32 + rh * 16;

  bf16x8 qfrag[4];
  {
    const unsigned short* qp = qbf + ((size_t)(qrow + rl) * NQ + n) * H + g * 8;
#pragma unroll
    for (int ks = 0; ks < 4; ++ks) qfrag[ks] = *(const bf16x8*)(qp + ks * 32);
  }

  f32x4 oacc[8];
#pragma unroll
  for (int ob = 0; ob < 8; ++ob) oacc[ob] = (f32x4){0.f, 0.f, 0.f, 0.f};
  float mrun[4] = {-1e30f, -1e30f, -1e30f, -1e30f};
  float lrun[4] = {0.f, 0.f, 0.f, 0.f};

  // staging maps (512 threads): K 64x128, Vt 128x64, 16 cols/thread each
  const int krow = tid >> 3, kseg = (tid & 7) * 16;
  const int vh = tid >> 2, vseg = (tid & 3) * 16;

  const int ktmax = (qb * 32 + 31) >> 6;
  // T14: preload tile 0 into regs; per-tile {write LDS; issue next loads; compute}
  bf16x8 krA, krB, vrA, vrB;
  {
    const unsigned short* kp = kbf + ((size_t)krow * NKV + kvh) * H + kseg;
    krA = *(const bf16x8*)kp;
    krB = *(const bf16x8*)(kp + 8);
    const unsigned short* vp = vtbf + (size_t)(kvh * H + vh) * T + vseg;
    vrA = *(const bf16x8*)vp;
    vrB = *(const bf16x8*)(vp + 8);
  }
  for (int kt = 0; kt <= ktmax; ++kt) {
    const int kbase = kt * 64;
    __syncthreads();  // previous tile's readers done
    *(bf16x8*)&K_lds[krow * KLD + kseg] = krA;
    *(bf16x8*)&K_lds[krow * KLD + kseg + 8] = krB;
    *(bf16x8*)&Vt_lds[vh * VLD + vseg] = vrA;
    *(bf16x8*)&Vt_lds[vh * VLD + vseg + 8] = vrB;
    if (kt < ktmax) {  // issue next-tile loads; land under this tile's compute
      const unsigned short* kp =
          kbf + ((size_t)(kbase + 64 + krow) * NKV + kvh) * H + kseg;
      krA = *(const bf16x8*)kp;
      krB = *(const bf16x8*)(kp + 8);
      const unsigned short* vp =
          vtbf + (size_t)(kvh * H + vh) * T + kbase + 64 + vseg;
      vrA = *(const bf16x8*)vp;
      vrB = *(const bf16x8*)(vp + 8);
    }
    __syncthreads();

    f32x4 sacc[4];
#pragma unroll
    for (int cb = 0; cb < 4; ++cb) sacc[cb] = (f32x4){0.f, 0.f, 0.f, 0.f};
#pragma unroll
    for (int cb = 0; cb < 4; ++cb)
#pragma unroll
      for (int ks = 0; ks < 4; ++ks) {
        bf16x8 kf = *(const bf16x8*)&K_lds[(cb * 16 + rl) * KLD + ks * 32 + g * 8];
        sacc[cb] = MFMA16(qfrag[ks], kf, sacc[cb]);
      }

    if (kt == ktmax) {  // causal mask, absolute indices
#pragma unroll
      for (int cb = 0; cb < 4; ++cb) {
        int kv_abs = kbase + cb * 16 + rl;
#pragma unroll
        for (int r = 0; r < 4; ++r) {
          if (kv_abs > qrow + g * 4 + r) sacc[cb][r] = -1e30f;
        }
      }
    }

    float mx[4], sm[4], corr[4];
#pragma unroll
    for (int r = 0; r < 4; ++r) {
      float m0 = fmaxf(fmaxf(sacc[0][r], sacc[1][r]), fmaxf(sacc[2][r], sacc[3][r]));
#pragma unroll
      for (int off = 1; off < 16; off <<= 1) m0 = fmaxf(m0, __shfl_xor(m0, off, 64));
      float nm = fmaxf(mrun[r], m0);
      corr[r] = __expf(mrun[r] - nm);
      mrun[r] = nm;
      mx[r] = nm;
    }
#pragma unroll
    for (int cb = 0; cb < 4; ++cb)
#pragma unroll
      for (int r = 0; r < 4; ++r) sacc[cb][r] = __expf(sacc[cb][r] - mx[r]);
#pragma unroll
    for (int r = 0; r < 4; ++r) {
      float s0 = sacc[0][r] + sacc[1][r] + sacc[2][r] + sacc[3][r];
#pragma unroll
      for (int off = 1; off < 16; off <<= 1) s0 += __shfl_xor(s0, off, 64);
      sm[r] = s0;
      lrun[r] = lrun[r] * corr[r] + sm[r];
    }
#pragma unroll
    for (int ob = 0; ob < 8; ++ob)
#pragma unroll
      for (int r = 0; r < 4; ++r) oacc[ob][r] *= corr[r];

#pragma unroll
    for (int cb = 0; cb < 4; ++cb)
#pragma unroll
      for (int r = 0; r < 4; ++r)
        P_lds[(wv * 16 + g * 4 + r) * PLD + cb * 16 + rl] = f2bf(sacc[cb][r]);

    bf16x8 pa[2];
#pragma unroll
    for (int ks = 0; ks < 2; ++ks)
      pa[ks] = *(const bf16x8*)&P_lds[(wv * 16 + rl) * PLD + ks * 32 + g * 8];

#pragma unroll
    for (int ob = 0; ob < 8; ++ob)
#pragma unroll
      for (int ks = 0; ks < 2; ++ks) {
        bf16x8 vf = *(const bf16x8*)&Vt_lds[(ob * 16 + rl) * VLD + ks * 32 + g * 8];
        oacc[ob] = MFMA16(pa[ks], vf, oacc[ob]);
      }
  }

  float inv[4];
#pragma unroll
  for (int r = 0; r < 4; ++r) inv[r] = 1.f / lrun[r];
#pragma unroll
  for (int ob = 0; ob < 8; ++ob)
#pragma unroll
    for (int r = 0; r < 4; ++r) {
      int t = qrow + g * 4 + r;
      out[((size_t)t * NQ + n) * H + ob * 16 + rl] = f2bf(oacc[ob][r] * inv[r]);
    }
}

extern "C" void kernel_launch(void* const* d_in, const int* in_sizes, int n_in,
                              void* d_out, int out_size, void* d_ws, size_t ws_size,
                              hipStream_t stream) {
  (void)in_sizes; (void)n_in; (void)out_size; (void)ws_size;
  const float* x = (const float*)d_in[0];
  const int* positions = (const int*)d_in[1];
  const float* ln1 = (const float*)d_in[2];
  const float* w_q = (const float*)d_in[3];
  const float* w_k = (const float*)d_in[4];
  const float* w_v = (const float*)d_in[5];
  const float* w_o = (const float*)d_in[6];
  const float* ln2 = (const float*)d_in[7];
  const float* w_gate = (const float*)d_in[8];
  const float* w_up = (const float*)d_in[9];
  const float* w_down = (const float*)d_in[10];
  float* out = (float*)d_out;

  char* ws = (char*)d_ws;
  size_t off = 0;
  auto alloc = [&](size_t bytes) {
    char* p = ws + off;
    off += (bytes + 255) & ~(size_t)255;
    return p;
  };
  unsigned short* h_bf = (unsigned short*)alloc((size_t)T * D * 2);
  unsigned short* h2_bf = (unsigned short*)alloc((size_t)T * D * 2);
  unsigned short* attn_bf = (unsigned short*)alloc((size_t)T * NQ * H * 2);
  unsigned short* act_bf = (unsigned short*)alloc((size_t)T * F * 2);
  float* qkvf = (float*)alloc((size_t)T * NQKV * 4);
  float* resid = (float*)alloc((size_t)T * D * 4);
  float* ctab = (float*)alloc((size_t)T * 64 * 4);
  float* stab = (float*)alloc((size_t)T * 64 * 4);
  unsigned short* qbf = (unsigned short*)alloc((size_t)T * NQ * H * 2);
  unsigned short* kbf = (unsigned short*)alloc((size_t)T * NKV * H * 2);
  unsigned short* vtbf = (unsigned short*)alloc((size_t)NKV * H * T * 2);
  unsigned short* wqkvt = (unsigned short*)alloc((size_t)NQKV * D * 2);
  unsigned short* wot = (unsigned short*)alloc((size_t)D * NQ * H * 2);
  unsigned short* wgut = (unsigned short*)alloc((size_t)2 * F * D * 2);
  unsigned short* wdt = (unsigned short*)alloc((size_t)D * F * 2);
  // K-split partial buffers aliased onto dead regions (each needs T*D*4 = 33.6MB)
  float* part0 = qkvf;            // qkvf: 50.3MB, dead after rope_bf16
  float* part1 = (float*)wqkvt;   // wqkvt: 50.3MB, dead after QKV GEMM

  transpose_bf16<0><<<dim3(D / 64, (NQ * H) / 64), 256, 0, stream>>>(w_q, wqkvt, D, NQ * H);
  transpose_bf16<0><<<dim3(D / 64, (NKV * H) / 64), 256, 0, stream>>>(
      w_k, wqkvt + (size_t)NQ * H * D, D, NKV * H);
  transpose_bf16<0><<<dim3(D / 64, (NKV * H) / 64), 256, 0, stream>>>(
      w_v, wqkvt + (size_t)VOFF * D, D, NKV * H);
  transpose_bf16<0><<<dim3((NQ * H) / 64, D / 64), 256, 0, stream>>>(w_o, wot, NQ * H, D);
  transpose_bf16<1><<<dim3(D / 64, F / 64), 256, 0, stream>>>(w_gate, wgut, D, F);
  transpose_bf16<2><<<dim3(D / 64, F / 64), 256, 0, stream>>>(w_up, wgut, D, F);
  transpose_bf16<0><<<dim3(F / 64, D / 64), 256, 0, stream>>>(w_down, wdt, F, D);

  rmsnorm_kernel<<<T, 256, 0, stream>>>(x, ln1, h_bf);
  rope_table<<<(T * 64) / 256, 256, 0, stream>>>(positions, ctab, stab);
  // QKV on 256² structure: q/k -> qkvf f32, V -> vtbf bf16 transposed
  gemm256<4><<<dim3(T / 256, NQKV / 256, 1), 512, 0, stream>>>(
      h_bf, wqkvt, qkvf, nullptr, vtbf, D, NQKV, D);
  rope_bf16<<<(T * NQ * 64) / 256, 256, 0, stream>>>(qkvf, ctab, stab, qbf, NQ, NQKV,
                                                     0.08838834764831845f);
  rope_bf16<<<(T * NKV * 64) / 256, 256, 0, stream>>>(qkvf + NQ * H, ctab, stab, kbf,
                                                      NKV, NQKV, 1.0f);
  flash_attn<<<dim3(T / 32, NKV), 512, 0, stream>>>(qbf, kbf, vtbf, attn_bf);
  // O-proj: 256² K-split x2 (full machine) -> partials
  gemm256<0><<<dim3(T / 256, D / 256, 2), 512, 0, stream>>>(
      attn_bf, wot, part0, part1, nullptr, NQ * H, D, NQ * H / 2);
  // fused: resid = p0+p1+x ; h2 = rmsnorm(resid)*ln2
  rmsnorm_add3<<<T, 256, 0, stream>>>(part0, part1, x, ln2, resid, h2_bf);
  // 256² interleaved gate/up GEMM
  gemm256<5><<<dim3(T / 256, (2 * F) / 256), 512, 0, stream>>>(
      h2_bf, wgut, nullptr, nullptr, act_bf, D, 2 * F, D);
  // down-proj: 256² K-split x2 -> partials, then out = p0+p1+resid
  gemm256<0><<<dim3(T / 256, D / 256, 2), 512, 0, stream>>>(
      act_bf, wdt, part0, part1, nullptr, F, D, F / 2);
  add3_kernel<<<(T * D / 4) / 256, 256, 0, stream>>>(part0, part1, resid, out);
}

// Round 14
// 1276.132 us; speedup vs baseline: 1.0705x; 1.0429x over previous
//
#include <hip/hip_runtime.h>

typedef __attribute__((ext_vector_type(8))) short bf16x8;
typedef __attribute__((ext_vector_type(4))) float f32x4;

constexpr int T = 2048;
constexpr int D = 4096;
constexpr int NQ = 32;    // query heads
constexpr int NKV = 8;    // kv heads
constexpr int H = 128;    // head dim
constexpr int F = 14336;  // ffn dim
constexpr int NQKV = (NQ + 2 * NKV) * H;  // 6144 packed qkv cols
constexpr int VOFF = (NQ + NKV) * H;      // 5120 col offset of V

__device__ inline unsigned short f2bf(float f) {
  unsigned u = __float_as_uint(f);
  return (unsigned short)((u + 0x7FFFu + ((u >> 16) & 1u)) >> 16);
}

__device__ inline float bf2f(unsigned short u) {
  return __uint_as_float((unsigned)u << 16);
}

__device__ inline void gload_lds16(const void* g, void* l) {
  __builtin_amdgcn_global_load_lds((const __attribute__((address_space(1))) void*)g,
                                   (__attribute__((address_space(3))) void*)l, 16, 0, 0);
}

#define MFMA16(a, b, c) __builtin_amdgcn_mfma_f32_16x16x32_bf16(a, b, c, 0, 0, 0)

// ------- weight transpose+convert: (K,N) f32 -> (rowmap(N),K) bf16 -------
// MODE 0: row = n;  MODE 1: row = (n>>4)*32 + (n&15);  MODE 2: MODE1 + 16
template <int MODE>
__global__ __launch_bounds__(256) void transpose_bf16(const float* __restrict__ in,
                                                      unsigned short* __restrict__ out,
                                                      int K, int N) {
  __shared__ float tile[64 * 65];
  const int kb = blockIdx.x * 64;
  const int nb = blockIdx.y * 64;
  const int tid = threadIdx.x;
  const int r = tid >> 2;
  const int c4 = tid & 3;
#pragma unroll
  for (int i = 0; i < 4; ++i) {
    float4 v = *(const float4*)(in + (size_t)(kb + r) * N + nb + c4 * 16 + i * 4);
    *(float4*)&tile[r * 65 + c4 * 16 + i * 4] = v;
  }
  __syncthreads();
  const int n = tid >> 2;
  const int kq = tid & 3;
  int nsrc = nb + n;
  int prow = (MODE == 0) ? nsrc : ((nsrc >> 4) * 32 + (nsrc & 15) + (MODE == 2 ? 16 : 0));
#pragma unroll
  for (int half = 0; half < 2; ++half) {
    ushort4 o0, o1;
    int k0 = kq * 16 + half * 8;
    o0.x = f2bf(tile[(k0 + 0) * 65 + n]);
    o0.y = f2bf(tile[(k0 + 1) * 65 + n]);
    o0.z = f2bf(tile[(k0 + 2) * 65 + n]);
    o0.w = f2bf(tile[(k0 + 3) * 65 + n]);
    o1.x = f2bf(tile[(k0 + 4) * 65 + n]);
    o1.y = f2bf(tile[(k0 + 5) * 65 + n]);
    o1.z = f2bf(tile[(k0 + 6) * 65 + n]);
    o1.w = f2bf(tile[(k0 + 7) * 65 + n]);
    unsigned short* op = out + (size_t)prow * K + kb + k0;
    *(ushort4*)(op + 0) = o0;
    *(ushort4*)(op + 4) = o1;
  }
}

// ---------------- RMSNorm: f32 in -> bf16 out ----------------
__global__ __launch_bounds__(256) void rmsnorm_kernel(
    const float* __restrict__ in, const float* __restrict__ scale,
    unsigned short* __restrict__ out) {
  int row = blockIdx.x;
  const float4* xr = (const float4*)(in + (size_t)row * D);
  const float4* sr = (const float4*)scale;
  float4 vals[4];
  float ss = 0.f;
#pragma unroll
  for (int i = 0; i < 4; ++i) {
    float4 v = xr[threadIdx.x + i * 256];
    vals[i] = v;
    ss += v.x * v.x + v.y * v.y + v.z * v.z + v.w * v.w;
  }
#pragma unroll
  for (int off = 32; off; off >>= 1) ss += __shfl_xor(ss, off, 64);
  __shared__ float wsum[4];
  if ((threadIdx.x & 63) == 0) wsum[threadIdx.x >> 6] = ss;
  __syncthreads();
  float r = rsqrtf((wsum[0] + wsum[1] + wsum[2] + wsum[3]) * (1.f / D) + 1e-5f);
#pragma unroll
  for (int i = 0; i < 4; ++i) {
    int vi = threadIdx.x + i * 256;
    float4 v = vals[i];
    float4 s = sr[vi];
    ushort4 o;
    o.x = f2bf(v.x * r * s.x);
    o.y = f2bf(v.y * r * s.y);
    o.z = f2bf(v.z * r * s.z);
    o.w = f2bf(v.w * r * s.w);
    *(ushort4*)(out + (size_t)row * D + (size_t)vi * 4) = o;
  }
}

// ------- fused: resid = a+b+c (f32 out) ; h2 = rmsnorm(resid)*scale (bf16 out) -------
__global__ __launch_bounds__(256) void rmsnorm_add3(
    const float* __restrict__ a, const float* __restrict__ b,
    const float* __restrict__ c, const float* __restrict__ scale,
    float* __restrict__ residOut, unsigned short* __restrict__ out) {
  int row = blockIdx.x;
  const float4* ar = (const float4*)(a + (size_t)row * D);
  const float4* br = (const float4*)(b + (size_t)row * D);
  const float4* cr = (const float4*)(c + (size_t)row * D);
  const float4* sr = (const float4*)scale;
  float4* rr = (float4*)(residOut + (size_t)row * D);
  float4 vals[4];
  float ss = 0.f;
#pragma unroll
  for (int i = 0; i < 4; ++i) {
    int vi = threadIdx.x + i * 256;
    float4 va = ar[vi], vb = br[vi], vc = cr[vi];
    float4 v;
    v.x = va.x + vb.x + vc.x;
    v.y = va.y + vb.y + vc.y;
    v.z = va.z + vb.z + vc.z;
    v.w = va.w + vb.w + vc.w;
    vals[i] = v;
    ss += v.x * v.x + v.y * v.y + v.z * v.z + v.w * v.w;
  }
#pragma unroll
  for (int off = 32; off; off >>= 1) ss += __shfl_xor(ss, off, 64);
  __shared__ float wsum[4];
  if ((threadIdx.x & 63) == 0) wsum[threadIdx.x >> 6] = ss;
  __syncthreads();
  float r = rsqrtf((wsum[0] + wsum[1] + wsum[2] + wsum[3]) * (1.f / D) + 1e-5f);
#pragma unroll
  for (int i = 0; i < 4; ++i) {
    int vi = threadIdx.x + i * 256;
    float4 v = vals[i];
    rr[vi] = v;
    float4 s = sr[vi];
    ushort4 o;
    o.x = f2bf(v.x * r * s.x);
    o.y = f2bf(v.y * r * s.y);
    o.z = f2bf(v.z * r * s.z);
    o.w = f2bf(v.w * r * s.w);
    *(ushort4*)(out + (size_t)row * D + (size_t)vi * 4) = o;
  }
}

// ---------------- out = a + b + c (f32, vectorized) ----------------
__global__ __launch_bounds__(256) void add3_kernel(const float* __restrict__ a,
                                                   const float* __restrict__ b,
                                                   const float* __restrict__ c,
                                                   float* __restrict__ o) {
  int i = blockIdx.x * 256 + threadIdx.x;
  float4 va = ((const float4*)a)[i];
  float4 vb = ((const float4*)b)[i];
  float4 vc = ((const float4*)c)[i];
  float4 vo;
  vo.x = va.x + vb.x + vc.x;
  vo.y = va.y + vb.y + vc.y;
  vo.z = va.z + vb.z + vc.z;
  vo.w = va.w + vb.w + vc.w;
  ((float4*)o)[i] = vo;
}

// ---------------- RoPE cos/sin table ----------------
__global__ __launch_bounds__(256) void rope_table(const int* __restrict__ pos,
                                                  float* __restrict__ ctab,
                                                  float* __restrict__ stab) {
  int idx = blockIdx.x * 256 + threadIdx.x;  // T*64
  int t = idx >> 6, i = idx & 63;
  float inv = exp2f(-(float)i * (log2f(500000.0f) / 64.0f));
  float ang = (float)pos[t] * inv;
  ctab[idx] = cosf(ang);
  stab[idx] = sinf(ang);
}

// ------- RoPE apply: bf16 strided in -> bf16 out (scale folded) -------
__global__ __launch_bounds__(256) void rope_bf16(const unsigned short* __restrict__ x,
                                                 const float* __restrict__ ctab,
                                                 const float* __restrict__ stab,
                                                 unsigned short* __restrict__ out,
                                                 int nheads, int row_stride, float scale) {
  int idx = blockIdx.x * 256 + threadIdx.x;  // T*nheads*64
  int i = idx & 63;
  int tn = idx >> 6;
  int t = tn / nheads;
  int n = tn - t * nheads;
  float c = ctab[t * 64 + i], s = stab[t * 64 + i];
  const unsigned short* p = x + (size_t)t * row_stride + n * H;
  float x1 = bf2f(p[i]), x2 = bf2f(p[i + 64]);
  unsigned short* o = out + (size_t)tn * H;
  o[i] = f2bf((x1 * c - x2 * s) * scale);
  o[i + 64] = f2bf((x2 * c + x1 * s) * scale);
}

// ---------------- 256x256 single-barrier-per-phase GEMM, K-splittable ----------------
// (round-11 measured-best structure)
// A (M,K) bf16; Bt (N,K) bf16. 8 waves (2M x 4N), per-wave 128x64. BK=64.
// LDS 128KB dbuf. Swizzle both sides: byte_col ^= (row&7)<<4.
// ONE barrier per phase (after reads/stages, before MFMA). Even ds_read spread
// 8/4/8/4 via cross-tile B-lo pre-read in P3. Single vmcnt(6) per K-tile at P2.
// EP 0: outF/outF2 (by blockIdx.z) = acc (f32)
// EP 4: qkv: col<VOFF -> bf16 qk buffer (outF reinterpreted, stride VOFF);
//        else outB[(col-VOFF)*T+row] bf16 (V transposed)
// EP 5: Bt packed gate/up alternating 16-col groups; outB = bf16(silu(g)*u)
template <int EP>
__global__ __launch_bounds__(512, 2) void gemm256(
    const unsigned short* __restrict__ A, const unsigned short* __restrict__ Bt,
    float* __restrict__ outF, float* __restrict__ outF2,
    unsigned short* __restrict__ outB, int Kd, int Nd, int Klen) {
  __shared__ unsigned short lds[65536];
  const int tid = threadIdx.x, lane = tid & 63, wv = tid >> 6;
  const int wm = wv >> 2, wn = wv & 3;
  const int rl = lane & 15, g = lane >> 4;
  const int kz = blockIdx.z;
  // XCD-aware block swizzle within z-slice (gx*gy % 8 == 0)
  int raw = blockIdx.x + blockIdx.y * gridDim.x;
  int cpx = (gridDim.x * gridDim.y) >> 3;
  int sid = (raw & 7) * cpx + (raw >> 3);
  int brow = sid % gridDim.x;
  int bcol = sid / gridDim.x;
  const int m0 = brow * 256, n0 = bcol * 256;

  const int l8 = lane >> 3;
  const int scol = ((lane & 7) ^ l8) * 8;  // pre-swizzled global src col
  const int xr = (rl & 7) << 4;            // read-side swizzle
  const int pc0 = (g * 16) ^ xr;
  const int pc1 = (64 + g * 16) ^ xr;

  const char* ldsc = (const char*)lds;
  const unsigned short* gA = A + (size_t)(m0 + wv * 8 + l8) * Kd + kz * Klen + scol;
  const unsigned short* gB = Bt + (size_t)(n0 + wv * 8 + l8) * Kd + kz * Klen + scol;

  f32x4 acc[8][4];
#pragma unroll
  for (int i = 0; i < 8; ++i)
#pragma unroll
    for (int j = 0; j < 4; ++j) acc[i][j] = (f32x4){0.f, 0.f, 0.f, 0.f};

  const int NT = Klen >> 6;

// line l covers tile rows [l*64, l*64+64): LDS ushort off l*4096 + wv*512
#define STAGE_AL(kt, l)                                                      \
  gload_lds16(gA + (size_t)(kt) * 64 + (size_t)(l) * 64 * Kd,                \
              (void*)&lds[((kt) & 1) * 32768 + (l) * 4096 + wv * 512]);
#define STAGE_BL(kt, l)                                                      \
  gload_lds16(gB + (size_t)(kt) * 64 + (size_t)(l) * 64 * Kd,                \
              (void*)&lds[((kt) & 1) * 32768 + 16384 + (l) * 4096 + wv * 512]);
#define SBAR()                        \
  __builtin_amdgcn_sched_barrier(0);  \
  __builtin_amdgcn_s_barrier();

  // prologue: stage kt=0 and kt=1 fully, drain kt=0's 8 lines
  STAGE_AL(0, 0); STAGE_AL(0, 1); STAGE_AL(0, 2); STAGE_AL(0, 3);
  STAGE_BL(0, 0); STAGE_BL(0, 1); STAGE_BL(0, 2); STAGE_BL(0, 3);
  STAGE_AL(1, 0); STAGE_AL(1, 1); STAGE_AL(1, 2); STAGE_AL(1, 3);
  STAGE_BL(1, 0); STAGE_BL(1, 1); STAGE_BL(1, 2); STAGE_BL(1, 3);
  asm volatile("s_waitcnt vmcnt(8)" ::: "memory");
  SBAR();

  const int bhalf = (wn >> 1) * 16384;
  const int brl = (wn & 1) * 64;

  // pre-read B-lo of kt=0 (buffer 0; landed block-wide after prologue barrier)
  bf16x8 bLoC[2][2];
  {
    const char* bB0 = ldsc + 32768 + bhalf;
#pragma unroll
    for (int nf = 0; nf < 2; ++nf) {
      bLoC[nf][0] = *(const bf16x8*)(bB0 + (brl + nf * 16 + rl) * 128 + pc0);
      bLoC[nf][1] = *(const bf16x8*)(bB0 + (brl + nf * 16 + rl) * 128 + pc1);
    }
  }

  for (int kt = 0; kt < NT; ++kt) {
    const int b = kt & 1;
    const char* aB = ldsc + b * 65536 + wm * 16384;
    const char* bB = ldsc + b * 65536 + 32768 + bhalf;
    const char* bBn = ldsc + (b ^ 1) * 65536 + 32768 + bhalf;
    const bool pre = (kt + 2 < NT);
    bf16x8 aLo[4][2], aHi[4][2], bHi[2][2], bLoN[2][2];
    // ---- P0: read A-lo (8); | q0 = aLo x bLoC ----
#pragma unroll
    for (int mf = 0; mf < 4; ++mf) {
      aLo[mf][0] = *(const bf16x8*)(aB + (mf * 16 + rl) * 128 + pc0);
      aLo[mf][1] = *(const bf16x8*)(aB + (mf * 16 + rl) * 128 + pc1);
    }
    SBAR();
    __builtin_amdgcn_s_setprio(1);
#pragma unroll
    for (int mf = 0; mf < 4; ++mf)
#pragma unroll
      for (int nf = 0; nf < 2; ++nf) {
        acc[mf][nf] = MFMA16(aLo[mf][0], bLoC[nf][0], acc[mf][nf]);
        acc[mf][nf] = MFMA16(aLo[mf][1], bLoC[nf][1], acc[mf][nf]);
      }
    __builtin_amdgcn_s_setprio(0);
    // ---- P1: read B-hi (4); stage A(kt+2) lines 0,2; | q1 ----
#pragma unroll
    for (int nf = 0; nf < 2; ++nf) {
      bHi[nf][0] = *(const bf16x8*)(bB + (brl + (nf + 2) * 16 + rl) * 128 + pc0);
      bHi[nf][1] = *(const bf16x8*)(bB + (brl + (nf + 2) * 16 + rl) * 128 + pc1);
    }
    if (pre) { STAGE_AL(kt + 2, 0); STAGE_AL(kt + 2, 2); }
    SBAR();
    __builtin_amdgcn_s_setprio(1);
#pragma unroll
    for (int mf = 0; mf < 4; ++mf)
#pragma unroll
      for (int nf = 0; nf < 2; ++nf) {
        acc[mf][nf + 2] = MFMA16(aLo[mf][0], bHi[nf][0], acc[mf][nf + 2]);
        acc[mf][nf + 2] = MFMA16(aLo[mf][1], bHi[nf][1], acc[mf][nf + 2]);
      }
    __builtin_amdgcn_s_setprio(0);
    // ---- P2: read A-hi (8); stage B(kt+2) 4 lines; vmcnt; | q2 ----
#pragma unroll
    for (int mf = 0; mf < 4; ++mf) {
      aHi[mf][0] = *(const bf16x8*)(aB + ((mf + 4) * 16 + rl) * 128 + pc0);
      aHi[mf][1] = *(const bf16x8*)(aB + ((mf + 4) * 16 + rl) * 128 + pc1);
    }
    if (pre) {
      STAGE_BL(kt + 2, 0); STAGE_BL(kt + 2, 1);
      STAGE_BL(kt + 2, 2); STAGE_BL(kt + 2, 3);
      asm volatile("s_waitcnt vmcnt(6)" ::: "memory");  // drain all kt+1 lines
    } else {
      asm volatile("s_waitcnt vmcnt(0)" ::: "memory");  // tail: drain everything
    }
    SBAR();
    __builtin_amdgcn_s_setprio(1);
#pragma unroll
    for (int mf = 0; mf < 4; ++mf)
#pragma unroll
      for (int nf = 0; nf < 2; ++nf) {
        acc[mf + 4][nf + 2] = MFMA16(aHi[mf][0], bHi[nf][0], acc[mf + 4][nf + 2]);
        acc[mf + 4][nf + 2] = MFMA16(aHi[mf][1], bHi[nf][1], acc[mf + 4][nf + 2]);
      }
    __builtin_amdgcn_s_setprio(0);
    // ---- P3: stage A(kt+2) lines 1,3; pre-read B-lo(kt+1) (4); | q3 ----
    if (pre) { STAGE_AL(kt + 2, 1); STAGE_AL(kt + 2, 3); }
    if (kt + 1 < NT) {
#pragma unroll
      for (int nf = 0; nf < 2; ++nf) {
        bLoN[nf][0] = *(const bf16x8*)(bBn + (brl + nf * 16 + rl) * 128 + pc0);
        bLoN[nf][1] = *(const bf16x8*)(bBn + (brl + nf * 16 + rl) * 128 + pc1);
      }
    }
    SBAR();
    __builtin_amdgcn_s_setprio(1);
#pragma unroll
    for (int mf = 0; mf < 4; ++mf)
#pragma unroll
      for (int nf = 0; nf < 2; ++nf) {
        acc[mf + 4][nf] = MFMA16(aHi[mf][0], bLoC[nf][0], acc[mf + 4][nf]);
        acc[mf + 4][nf] = MFMA16(aHi[mf][1], bLoC[nf][1], acc[mf + 4][nf]);
      }
    __builtin_amdgcn_s_setprio(0);
    if (kt + 1 < NT) {
#pragma unroll
      for (int nf = 0; nf < 2; ++nf) {
        bLoC[nf][0] = bLoN[nf][0];
        bLoC[nf][1] = bLoN[nf][1];
      }
    }
  }

  const int g4 = g * 4;
  if constexpr (EP == 5) {
    const int acolBase = ((n0 + wn * 64) >> 1) + rl;
#pragma unroll
    for (int mf = 0; mf < 8; ++mf)
#pragma unroll
      for (int p = 0; p < 2; ++p) {
        int acol = acolBase + p * 16;
#pragma unroll
        for (int jj = 0; jj < 4; ++jj) {
          int row = m0 + wm * 128 + mf * 16 + g4 + jj;
          float gg = acc[mf][2 * p][jj];
          float uu = acc[mf][2 * p + 1][jj];
          outB[(size_t)row * F + acol] = f2bf(gg / (1.f + __expf(-gg)) * uu);
        }
      }
  } else if constexpr (EP == 4) {
    if (n0 >= VOFF) {
      // V region: bf16 transposed (NKV*H, T)
#pragma unroll
      for (int mf = 0; mf < 8; ++mf)
#pragma unroll
        for (int q = 0; q < 4; ++q) {
          int col = n0 + wn * 64 + q * 16 + rl;
          int row0 = m0 + wm * 128 + mf * 16 + g4;
          ushort4 o;
          o.x = f2bf(acc[mf][q][0]);
          o.y = f2bf(acc[mf][q][1]);
          o.z = f2bf(acc[mf][q][2]);
          o.w = f2bf(acc[mf][q][3]);
          *(ushort4*)&outB[(size_t)(col - VOFF) * T + row0] = o;
        }
    } else {
      // q/k region: bf16, stride VOFF (outF reinterpreted)
      unsigned short* qk = (unsigned short*)outF;
#pragma unroll
      for (int mf = 0; mf < 8; ++mf)
#pragma unroll
        for (int q = 0; q < 4; ++q) {
          int col = n0 + wn * 64 + q * 16 + rl;
#pragma unroll
          for (int jj = 0; jj < 4; ++jj) {
            int row = m0 + wm * 128 + mf * 16 + g4 + jj;
            qk[(size_t)row * VOFF + col] = f2bf(acc[mf][q][jj]);
          }
        }
    }
  } else {
    float* dst = kz ? outF2 : outF;
#pragma unroll
    for (int mf = 0; mf < 8; ++mf)
#pragma unroll
      for (int q = 0; q < 4; ++q) {
        int col = n0 + wn * 64 + q * 16 + rl;
#pragma unroll
        for (int jj = 0; jj < 4; ++jj) {
          int row = m0 + wm * 128 + mf * 16 + g4 + jj;
          dst[(size_t)row * Nd + col] = acc[mf][q][jj];
        }
      }
  }
#undef STAGE_AL
#undef STAGE_BL
#undef SBAR
}

// ---------------- Flash attention (MFMA), GQA group-shared K/V, T14 dbuf ----------------
constexpr int KLD = 136;
constexpr int VLD = 72;
constexpr int PLD = 72;

__global__ __launch_bounds__(512) void flash_attn(
    const unsigned short* __restrict__ qbf, const unsigned short* __restrict__ kbf,
    const unsigned short* __restrict__ vtbf, unsigned short* __restrict__ out) {
  __shared__ unsigned short K_lds[64 * KLD];
  __shared__ unsigned short Vt_lds[H * VLD];
  __shared__ unsigned short P_lds[8 * 16 * PLD];

  const int tid = threadIdx.x;
  const int lane = tid & 63;
  const int wv = tid >> 6;
  const int qb = blockIdx.x;   // 32-row q block
  const int kvh = blockIdx.y;  // kv head
  const int qh = wv & 3, rh = wv >> 2;
  const int n = kvh * 4 + qh;
  const int g = lane >> 4;
  const int rl = lane & 15;
  const int qrow = qb * 32 + rh * 16;

  bf16x8 qfrag[4];
  {
    const unsigned short* qp = qbf + ((size_t)(qrow + rl) * NQ + n) * H + g * 8;
#pragma unroll
    for (int ks = 0; ks < 4; ++ks) qfrag[ks] = *(const bf16x8*)(qp + ks * 32);
  }

  f32x4 oacc[8];
#pragma unroll
  for (int ob = 0; ob < 8; ++ob) oacc[ob] = (f32x4){0.f, 0.f, 0.f, 0.f};
  float mrun[4] = {-1e30f, -1e30f, -1e30f, -1e30f};
  float lrun[4] = {0.f, 0.f, 0.f, 0.f};

  const int krow = tid >> 3, kseg = (tid & 7) * 16;
  const int vh = tid >> 2, vseg = (tid & 3) * 16;

  const int ktmax = (qb * 32 + 31) >> 6;
  bf16x8 krA, krB, vrA, vrB;
  {
    const unsigned short* kp = kbf + ((size_t)krow * NKV + kvh) * H + kseg;
    krA = *(const bf16x8*)kp;
    krB = *(const bf16x8*)(kp + 8);
    const unsigned short* vp = vtbf + (size_t)(kvh * H + vh) * T + vseg;
    vrA = *(const bf16x8*)vp;
    vrB = *(const bf16x8*)(vp + 8);
  }
  for (int kt = 0; kt <= ktmax; ++kt) {
    const int kbase = kt * 64;
    __syncthreads();
    *(bf16x8*)&K_lds[krow * KLD + kseg] = krA;
    *(bf16x8*)&K_lds[krow * KLD + kseg + 8] = krB;
    *(bf16x8*)&Vt_lds[vh * VLD + vseg] = vrA;
    *(bf16x8*)&Vt_lds[vh * VLD + vseg + 8] = vrB;
    if (kt < ktmax) {
      const unsigned short* kp =
          kbf + ((size_t)(kbase + 64 + krow) * NKV + kvh) * H + kseg;
      krA = *(const bf16x8*)kp;
      krB = *(const bf16x8*)(kp + 8);
      const unsigned short* vp =
          vtbf + (size_t)(kvh * H + vh) * T + kbase + 64 + vseg;
      vrA = *(const bf16x8*)vp;
      vrB = *(const bf16x8*)(vp + 8);
    }
    __syncthreads();

    f32x4 sacc[4];
#pragma unroll
    for (int cb = 0; cb < 4; ++cb) sacc[cb] = (f32x4){0.f, 0.f, 0.f, 0.f};
#pragma unroll
    for (int cb = 0; cb < 4; ++cb)
#pragma unroll
      for (int ks = 0; ks < 4; ++ks) {
        bf16x8 kf = *(const bf16x8*)&K_lds[(cb * 16 + rl) * KLD + ks * 32 + g * 8];
        sacc[cb] = MFMA16(qfrag[ks], kf, sacc[cb]);
      }

    if (kt == ktmax) {
#pragma unroll
      for (int cb = 0; cb < 4; ++cb) {
        int kv_abs = kbase + cb * 16 + rl;
#pragma unroll
        for (int r = 0; r < 4; ++r) {
          if (kv_abs > qrow + g * 4 + r) sacc[cb][r] = -1e30f;
        }
      }
    }

    float mx[4], sm[4], corr[4];
#pragma unroll
    for (int r = 0; r < 4; ++r) {
      float m0 = fmaxf(fmaxf(sacc[0][r], sacc[1][r]), fmaxf(sacc[2][r], sacc[3][r]));
#pragma unroll
      for (int off = 1; off < 16; off <<= 1) m0 = fmaxf(m0, __shfl_xor(m0, off, 64));
      float nm = fmaxf(mrun[r], m0);
      corr[r] = __expf(mrun[r] - nm);
      mrun[r] = nm;
      mx[r] = nm;
    }
#pragma unroll
    for (int cb = 0; cb < 4; ++cb)
#pragma unroll
      for (int r = 0; r < 4; ++r) sacc[cb][r] = __expf(sacc[cb][r] - mx[r]);
#pragma unroll
    for (int r = 0; r < 4; ++r) {
      float s0 = sacc[0][r] + sacc[1][r] + sacc[2][r] + sacc[3][r];
#pragma unroll
      for (int off = 1; off < 16; off <<= 1) s0 += __shfl_xor(s0, off, 64);
      sm[r] = s0;
      lrun[r] = lrun[r] * corr[r] + sm[r];
    }
#pragma unroll
    for (int ob = 0; ob < 8; ++ob)
#pragma unroll
      for (int r = 0; r < 4; ++r) oacc[ob][r] *= corr[r];

#pragma unroll
    for (int cb = 0; cb < 4; ++cb)
#pragma unroll
      for (int r = 0; r < 4; ++r)
        P_lds[(wv * 16 + g * 4 + r) * PLD + cb * 16 + rl] = f2bf(sacc[cb][r]);

    bf16x8 pa[2];
#pragma unroll
    for (int ks = 0; ks < 2; ++ks)
      pa[ks] = *(const bf16x8*)&P_lds[(wv * 16 + rl) * PLD + ks * 32 + g * 8];

#pragma unroll
    for (int ob = 0; ob < 8; ++ob)
#pragma unroll
      for (int ks = 0; ks < 2; ++ks) {
        bf16x8 vf = *(const bf16x8*)&Vt_lds[(ob * 16 + rl) * VLD + ks * 32 + g * 8];
        oacc[ob] = MFMA16(pa[ks], vf, oacc[ob]);
      }
  }

  float inv[4];
#pragma unroll
  for (int r = 0; r < 4; ++r) inv[r] = 1.f / lrun[r];
#pragma unroll
  for (int ob = 0; ob < 8; ++ob)
#pragma unroll
    for (int r = 0; r < 4; ++r) {
      int t = qrow + g * 4 + r;
      out[((size_t)t * NQ + n) * H + ob * 16 + rl] = f2bf(oacc[ob][r] * inv[r]);
    }
}

extern "C" void kernel_launch(void* const* d_in, const int* in_sizes, int n_in,
                              void* d_out, int out_size, void* d_ws, size_t ws_size,
                              hipStream_t stream) {
  (void)in_sizes; (void)n_in; (void)out_size; (void)ws_size;
  const float* x = (const float*)d_in[0];
  const int* positions = (const int*)d_in[1];
  const float* ln1 = (const float*)d_in[2];
  const float* w_q = (const float*)d_in[3];
  const float* w_k = (const float*)d_in[4];
  const float* w_v = (const float*)d_in[5];
  const float* w_o = (const float*)d_in[6];
  const float* ln2 = (const float*)d_in[7];
  const float* w_gate = (const float*)d_in[8];
  const float* w_up = (const float*)d_in[9];
  const float* w_down = (const float*)d_in[10];
  float* out = (float*)d_out;

  char* ws = (char*)d_ws;
  size_t off = 0;
  auto alloc = [&](size_t bytes) {
    char* p = ws + off;
    off += (bytes + 255) & ~(size_t)255;
    return p;
  };
  unsigned short* h_bf = (unsigned short*)alloc((size_t)T * D * 2);
  unsigned short* h2_bf = (unsigned short*)alloc((size_t)T * D * 2);
  unsigned short* attn_bf = (unsigned short*)alloc((size_t)T * NQ * H * 2);
  unsigned short* act_bf = (unsigned short*)alloc((size_t)T * F * 2);
  float* qkvf = (float*)alloc((size_t)T * NQKV * 4);  // also holds bf16 qk (aliased)
  float* resid = (float*)alloc((size_t)T * D * 4);
  float* ctab = (float*)alloc((size_t)T * 64 * 4);
  float* stab = (float*)alloc((size_t)T * 64 * 4);
  unsigned short* qbf = (unsigned short*)alloc((size_t)T * NQ * H * 2);
  unsigned short* kbf = (unsigned short*)alloc((size_t)T * NKV * H * 2);
  unsigned short* vtbf = (unsigned short*)alloc((size_t)NKV * H * T * 2);
  unsigned short* wqkvt = (unsigned short*)alloc((size_t)NQKV * D * 2);
  unsigned short* wot = (unsigned short*)alloc((size_t)D * NQ * H * 2);
  unsigned short* wgut = (unsigned short*)alloc((size_t)2 * F * D * 2);
  unsigned short* wdt = (unsigned short*)alloc((size_t)D * F * 2);
  // K-split partial buffers aliased onto dead regions (each needs T*D*4 = 33.6MB)
  float* part0 = qkvf;            // qkvf: 50.3MB, dead after rope_bf16
  float* part1 = (float*)wqkvt;   // wqkvt: 50.3MB, dead after QKV GEMM
  unsigned short* qkbf = (unsigned short*)qkvf;  // bf16 qk, stride VOFF

  transpose_bf16<0><<<dim3(D / 64, (NQ * H) / 64), 256, 0, stream>>>(w_q, wqkvt, D, NQ * H);
  transpose_bf16<0><<<dim3(D / 64, (NKV * H) / 64), 256, 0, stream>>>(
      w_k, wqkvt + (size_t)NQ * H * D, D, NKV * H);
  transpose_bf16<0><<<dim3(D / 64, (NKV * H) / 64), 256, 0, stream>>>(
      w_v, wqkvt + (size_t)VOFF * D, D, NKV * H);
  transpose_bf16<0><<<dim3((NQ * H) / 64, D / 64), 256, 0, stream>>>(w_o, wot, NQ * H, D);
  transpose_bf16<1><<<dim3(D / 64, F / 64), 256, 0, stream>>>(w_gate, wgut, D, F);
  transpose_bf16<2><<<dim3(D / 64, F / 64), 256, 0, stream>>>(w_up, wgut, D, F);
  transpose_bf16<0><<<dim3(F / 64, D / 64), 256, 0, stream>>>(w_down, wdt, F, D);

  rmsnorm_kernel<<<T, 256, 0, stream>>>(x, ln1, h_bf);
  rope_table<<<(T * 64) / 256, 256, 0, stream>>>(positions, ctab, stab);
  // QKV on 256² structure: q/k -> qkbf bf16 (stride VOFF), V -> vtbf bf16 transposed
  gemm256<4><<<dim3(T / 256, NQKV / 256, 1), 512, 0, stream>>>(
      h_bf, wqkvt, qkvf, nullptr, vtbf, D, NQKV, D);
  rope_bf16<<<(T * NQ * 64) / 256, 256, 0, stream>>>(qkbf, ctab, stab, qbf, NQ, VOFF,
                                                     0.08838834764831845f);
  rope_bf16<<<(T * NKV * 64) / 256, 256, 0, stream>>>(qkbf + NQ * H, ctab, stab, kbf,
                                                      NKV, VOFF, 1.0f);
  flash_attn<<<dim3(T / 32, NKV), 512, 0, stream>>>(qbf, kbf, vtbf, attn_bf);
  // O-proj: 256² K-split x2 (full machine) -> partials
  gemm256<0><<<dim3(T / 256, D / 256, 2), 512, 0, stream>>>(
      attn_bf, wot, part0, part1, nullptr, NQ * H, D, NQ * H / 2);
  // fused: resid = p0+p1+x ; h2 = rmsnorm(resid)*ln2
  rmsnorm_add3<<<T, 256, 0, stream>>>(part0, part1, x, ln2, resid, h2_bf);
  // 256² interleaved gate/up GEMM
  gemm256<5><<<dim3(T / 256, (2 * F) / 256), 512, 0, stream>>>(
      h2_bf, wgut, nullptr, nullptr, act_bf, D, 2 * F, D);
  // down-proj: 256² K-split x2 -> partials, then out = p0+p1+resid
  gemm256<0><<<dim3(T / 256, D / 256, 2), 512, 0, stream>>>(
      act_bf, wdt, part0, part1, nullptr, F, D, F / 2);
  add3_kernel<<<(T * D / 4) / 256, 256, 0, stream>>>(part0, part1, resid, out);
}